// Round 1
// baseline (61.896 us; speedup 1.0000x reference)
//
#include <hip/hip_runtime.h>

// SumFunc: per-row softmax(d1), softmax(d2) over 10 logits, then full 1-D
// convolution -> 19 outputs. B = 2,097,152 rows. Memory-bound (~327 MB).

constexpr int D   = 10;   // digit range
constexpr int S   = 19;   // 2*D - 1
constexpr int BLK = 256;  // threads per block, 1 row per thread

__global__ __launch_bounds__(BLK) void sumfunc_kernel(
    const float* __restrict__ d1, const float* __restrict__ d2,
    float* __restrict__ out, int n)
{
    // Output staging: 256 rows * 19 floats = 19 KB LDS.
    __shared__ float so[BLK * S];

    const int tid = threadIdx.x;
    const long long row = (long long)blockIdx.x * BLK + tid;

    if (row < n) {
        // Direct row loads: 5 x float2 each (row*40 bytes is 8-aligned).
        const float2* p1 = reinterpret_cast<const float2*>(d1 + row * D);
        const float2* p2 = reinterpret_cast<const float2*>(d2 + row * D);
        float a[D], b[D];
        #pragma unroll
        for (int i = 0; i < 5; ++i) {
            float2 v1 = p1[i];
            float2 v2 = p2[i];
            a[2*i] = v1.x; a[2*i+1] = v1.y;
            b[2*i] = v2.x; b[2*i+1] = v2.y;
        }

        // Stable unnormalized softmax numerators; normalize at the end.
        float m1 = a[0], m2 = b[0];
        #pragma unroll
        for (int i = 1; i < D; ++i) {
            m1 = fmaxf(m1, a[i]);
            m2 = fmaxf(m2, b[i]);
        }
        float s1 = 0.f, s2 = 0.f;
        #pragma unroll
        for (int i = 0; i < D; ++i) {
            a[i] = __expf(a[i] - m1); s1 += a[i];
            b[i] = __expf(b[i] - m2); s2 += b[i];
        }
        const float inv = 1.0f / (s1 * s2);

        // Full convolution: c[i+j] += a[i]*b[j]  (100 FMAs).
        float c[S];
        #pragma unroll
        for (int k = 0; k < S; ++k) c[k] = 0.f;
        #pragma unroll
        for (int i = 0; i < D; ++i) {
            #pragma unroll
            for (int j = 0; j < D; ++j) {
                c[i + j] = fmaf(a[i], b[j], c[i + j]);
            }
        }

        // Stage scaled results in LDS in row-major tile order.
        // Write stride 19 (odd) -> only 2-way bank aliasing over 64 lanes (free).
        #pragma unroll
        for (int k = 0; k < S; ++k) so[tid * S + k] = c[k] * inv;
    }
    __syncthreads();

    // Coalesced store: flat tile element e = k*BLK + tid maps to so[e].
    const long long base  = (long long)blockIdx.x * (BLK * S);
    const long long total = (long long)n * S;
    #pragma unroll
    for (int k = 0; k < S; ++k) {
        long long idx = base + (long long)k * BLK + tid;
        if (idx < total) out[idx] = so[k * BLK + tid];
    }
}

extern "C" void kernel_launch(void* const* d_in, const int* in_sizes, int n_in,
                              void* d_out, int out_size, void* d_ws, size_t ws_size,
                              hipStream_t stream) {
    const float* d1 = (const float*)d_in[0];
    const float* d2 = (const float*)d_in[1];
    float* out = (float*)d_out;
    const int n = in_sizes[0] / D;            // number of rows
    const int grid = (n + BLK - 1) / BLK;
    sumfunc_kernel<<<grid, BLK, 0, stream>>>(d1, d2, out, n);
}